// Round 4
// baseline (3239.607 us; speedup 1.0000x reference)
//
#include <hip/hip_runtime.h>

// Problem constants
#define Bn 4
#define Nn 8192
#define Dn 64
#define Sn 2048
#define Kn 32
#define R2c 0.04f          // f32(0.2*0.2) — same bits as np/jax weak-scalar cast
#define OUT_XYZ (Bn*Sn*3)  // 24576 floats of new_xyz, then feats

// Workspace layout (units = 4-byte elements)
#define WS_XS  0            // [B*N] x coords (SoA)
#define WS_YS  32768
#define WS_ZS  65536
#define WS_W1T 98304        // W1^T [67][64]
#define WS_W2T 102592       // W2^T [64][128]
#define WS_W3T 110784       // W3^T [128][256]
#define WS_GRP 143552       // int grp_idx [B*S][K]

#define KPAD 36             // padded LDS row stride (floats) for h tiles

// ---------------------------------------------------------------------------
// Prep: transpose xyz -> SoA and weights -> [C][O] layout
// ---------------------------------------------------------------------------
__global__ __launch_bounds__(256) void prep_kernel(const float* __restrict__ xyz,
                                                   const float* __restrict__ W1,
                                                   const float* __restrict__ W2,
                                                   const float* __restrict__ W3,
                                                   float* __restrict__ ws) {
    int id = blockIdx.x * 256 + threadIdx.x;
    if (id < Bn * Nn) {
        ws[WS_XS + id] = xyz[id * 3 + 0];
        ws[WS_YS + id] = xyz[id * 3 + 1];
        ws[WS_ZS + id] = xyz[id * 3 + 2];
    }
    int i1 = id - Bn * Nn;
    if (i1 >= 0 && i1 < 64 * 67)  { int o = i1 / 67,  c = i1 % 67;  ws[WS_W1T + c * 64  + o] = W1[i1]; }
    int i2 = i1 - 64 * 67;
    if (i2 >= 0 && i2 < 128 * 64) { int o = i2 / 64,  c = i2 % 64;  ws[WS_W2T + c * 128 + o] = W2[i2]; }
    int i3 = i2 - 128 * 64;
    if (i3 >= 0 && i3 < 256 * 128){ int o = i3 / 128, c = i3 % 128; ws[WS_W3T + c * 256 + o] = W3[i3]; }
}

// ---------------------------------------------------------------------------
// Farthest point sampling — restructured reduction, bit-exact f32 distances.
//   * distance math mirrors numpy: (dx*dx+dy*dy)+dz*dz, contract off, fminf
//   * argmax via packed u64 key (float bits monotone for dist>=0; low word
//     = ~p gives min-index tie-break == np.argmax first occurrence)
//   * 2 barriers/step (was 3 + LDS atomicMin): B1 after wave-key publish,
//     B2 after owner publishes centroid float4
//   * key slots double-buffered by parity (no barrier between step-s read
//     and step-(s+1) write); sCent is barrier-separated -> single buffer
// One workgroup per batch, 512 threads, 16 pts/thread in registers.
// ---------------------------------------------------------------------------
__global__ __launch_bounds__(512) void fps_kernel(const float* __restrict__ ws,
                                                  float* __restrict__ out_xyz) {
    #pragma clang fp contract(off)
    const int b = blockIdx.x;
    const int tid = threadIdx.x;
    const float* xs = ws + WS_XS + b * Nn;
    const float* ys = ws + WS_YS + b * Nn;
    const float* zs = ws + WS_ZS + b * Nn;

    float px[16], py[16], pz[16], dist[16];
    #pragma unroll
    for (int j = 0; j < 16; j++) {
        int p = j * 512 + tid;           // coalesced: lane-contiguous
        px[j] = xs[p]; py[j] = ys[p]; pz[j] = zs[p];
        dist[j] = 1e10f;                 // matches np.float32(1e10)
    }

    __shared__ unsigned long long sKey[2][8];
    __shared__ float4 sCent;

    // initial centroid = point 0 of the batch (broadcast global read, once)
    float cx = xs[0], cy = ys[0], cz = zs[0];

    for (int s = 0; s < Sn; s++) {
        const int par = s & 1;
        if (tid == 0) {
            int g = b * Sn + s;
            out_xyz[g * 3 + 0] = cx;     // emit current centroid (carry)
            out_xyz[g * 3 + 1] = cy;
            out_xyz[g * 3 + 2] = cz;
        }
        // distance update + inline first-occurrence argmax — exact ref op order
        float lmax = -1.0f;
        int jbest = 0;
        #pragma unroll
        for (int j = 0; j < 16; j++) {
            float dx = px[j] - cx, dy = py[j] - cy, dz = pz[j] - cz;
            float d  = (dx * dx + dy * dy) + dz * dz;
            float dm = fminf(dist[j], d);
            dist[j] = dm;
            bool c = dm > lmax;          // strict > keeps earliest j (min p)
            jbest = c ? j : jbest;
            lmax  = c ? dm : lmax;
        }
        int pbest = jbest * 512 + tid;
        unsigned long long key =
            ((unsigned long long)__float_as_uint(lmax) << 32) |
            (unsigned long long)(0xFFFFFFFFu - (unsigned)pbest);
        // wave butterfly max on the packed key (value major, min-p tie-break)
        #pragma unroll
        for (int off = 32; off >= 1; off >>= 1) {
            unsigned long long o = __shfl_xor(key, off);
            key = (key > o) ? key : o;
        }
        if ((tid & 63) == 0) sKey[par][tid >> 6] = key;
        __syncthreads();                               // B1: wave keys ready
        // every thread reduces the 8 wave keys (redundant, no 2nd round-trip)
        unsigned long long k = sKey[par][0];
        #pragma unroll
        for (int i = 1; i < 8; i++) {
            unsigned long long o = sKey[par][i];
            k = (k > o) ? k : o;
        }
        int p = (int)(0xFFFFFFFFu - (unsigned)(k & 0xFFFFFFFFull));
        if (tid == (p & 511)) {                        // owner has coords in regs
            int j = p >> 9;
            sCent = make_float4(px[j], py[j], pz[j], 0.f);
        }
        __syncthreads();                               // B2: centroid ready
        float4 c4 = sCent;                             // broadcast b128 read
        cx = c4.x; cy = c4.y; cz = c4.z;
    }
}

// ---------------------------------------------------------------------------
// Ball query, f32, mirroring the numpy transpile with einsum lowered to
// BLAS sgemm: the k=3 dot is an FMA chain acc=fma(a_k,b_k,acc) from 0.
// Norm terms are plain mul/add ((x2+y2)+z2). sq = (t1+t2) - 2*dot.
// One wave per (b,s). First K hits in ascending index order via
// ballot + prefix-popcount, early exit, pad with first hit.
// ---------------------------------------------------------------------------
__global__ __launch_bounds__(256) void ballq_kernel(const float* __restrict__ ws,
                                                    const float* __restrict__ newxyz,
                                                    int* __restrict__ grp) {
    #pragma clang fp contract(off)
    int t = blockIdx.x * 256 + threadIdx.x;
    int wid = t >> 6;            // 0..8191  (b*S+s)
    int lane = t & 63;
    int b = wid >> 11;
    const float* xs = ws + WS_XS + b * Nn;
    const float* ys = ws + WS_YS + b * Nn;
    const float* zs = ws + WS_ZS + b * Nn;

    float nx = newxyz[wid * 3 + 0], ny = newxyz[wid * 3 + 1], nz = newxyz[wid * 3 + 2];
    float a2 = (nx * nx + ny * ny) + nz * nz;   // np.sum(new**2, -1): plain mul/add

    int total = 0;
    int firstp = 0;
    for (int c = 0; c < Nn / 64; c++) {
        int p = c * 64 + lane;
        float x = xs[p], y = ys[p], z = zs[p];
        float bv = (x * x + y * y) + z * z;          // np.sum(xyz**2, -1)
        // sgemm k-loop: FMA rank-1 updates in order, acc starts at 0
        float dot = __builtin_fmaf(nx, x, 0.0f);
        dot = __builtin_fmaf(ny, y, dot);
        dot = __builtin_fmaf(nz, z, dot);
        float sq = (a2 + bv) - 2.0f * dot;           // (t1+t2) - 2*e
        bool hit = !(sq > R2c);
        unsigned long long mask = __ballot(hit);
        if (mask) {
            if (total == 0) firstp = c * 64 + (__ffsll(mask) - 1);
            int rank = __popcll(mask & ((1ull << lane) - 1ull));
            int slot = total + rank;
            if (hit && slot < Kn) grp[wid * Kn + slot] = p;
            total += (int)__popcll(mask);
            if (total >= Kn) break;
        }
    }
    if (lane >= total && lane < Kn) grp[wid * Kn + lane] = firstp;  // pad w/ first hit
}

// ---------------------------------------------------------------------------
// Fused gather + 3-layer MLP + maxpool (f32 — error ~1e-5 « 0.064 budget).
// One workgroup per (b,s) group. h tiles live transposed [C][K] in LDS
// (row stride KPAD=36, bank-friendly, 16B aligned). Weights read from global
// transposed copies (L1/L2 resident). Thread tile: 4 k-rows x WO outputs.
// ---------------------------------------------------------------------------
template<int C, int O, int WO>
__device__ __forceinline__ void mlp_layer(const float* inT, float* outT,
                                          const float* __restrict__ wt,
                                          const float* __restrict__ bias,
                                          int kt, int ot) {
    float acc[4][WO];
    #pragma unroll
    for (int oo = 0; oo < WO; oo++) {
        float bb = bias[ot * WO + oo];
        #pragma unroll
        for (int kk = 0; kk < 4; kk++) acc[kk][oo] = bb;
    }
    for (int c = 0; c < C; c++) {
        float4 hv = *(const float4*)&inT[c * KPAD + kt * 4];
        float ha[4] = {hv.x, hv.y, hv.z, hv.w};
        const float* wp = wt + c * O + ot * WO;
        float wv[WO];
        if constexpr (WO == 2) {
            float2 w = *(const float2*)wp; wv[0] = w.x; wv[1] = w.y;
        } else if constexpr (WO == 4) {
            float4 w = *(const float4*)wp; wv[0] = w.x; wv[1] = w.y; wv[2] = w.z; wv[3] = w.w;
        } else {
            float4 w0 = *(const float4*)wp, w1 = *(const float4*)(wp + 4);
            wv[0] = w0.x; wv[1] = w0.y; wv[2] = w0.z; wv[3] = w0.w;
            wv[4] = w1.x; wv[5] = w1.y; wv[6] = w1.z; wv[7] = w1.w;
        }
        #pragma unroll
        for (int kk = 0; kk < 4; kk++)
            #pragma unroll
            for (int oo = 0; oo < WO; oo++) acc[kk][oo] += ha[kk] * wv[oo];
    }
    #pragma unroll
    for (int oo = 0; oo < WO; oo++) {
        int o = ot * WO + oo;
        float4 st;
        st.x = fmaxf(acc[0][oo], 0.f); st.y = fmaxf(acc[1][oo], 0.f);
        st.z = fmaxf(acc[2][oo], 0.f); st.w = fmaxf(acc[3][oo], 0.f);
        *(float4*)&outT[o * KPAD + kt * 4] = st;
    }
}

__global__ __launch_bounds__(256) void mlp_kernel(const float* __restrict__ xyz,
                                                  const float* __restrict__ feat,
                                                  const float* __restrict__ ws,
                                                  const int* __restrict__ grp,
                                                  const float* __restrict__ b1,
                                                  const float* __restrict__ b2,
                                                  const float* __restrict__ b3,
                                                  float* __restrict__ out) {
    __shared__ float h0[67 * KPAD];
    __shared__ float h1[64 * KPAD];
    __shared__ float h2[128 * KPAD];
    __shared__ float mxs[8 * 256];
    __shared__ int   sIdx[Kn];
    __shared__ float sCent[3];

    int g = blockIdx.x;            // b*S + s
    int b = g >> 11;
    int tid = threadIdx.x;

    if (tid < Kn) sIdx[tid] = grp[g * Kn + tid];
    if (tid == 0) { sCent[0] = out[g*3]; sCent[1] = out[g*3+1]; sCent[2] = out[g*3+2]; }
    __syncthreads();

    { // gather: 8 threads per neighbor row
        int k = tid >> 3, m = tid & 7;
        int idx = sIdx[k];
        int base = b * Nn + idx;
        if (m == 0) {
            h0[0 * KPAD + k] = xyz[base * 3 + 0] - sCent[0];
            h0[1 * KPAD + k] = xyz[base * 3 + 1] - sCent[1];
            h0[2 * KPAD + k] = xyz[base * 3 + 2] - sCent[2];
        }
        const float4* f4 = (const float4*)(feat + base * 64 + m * 8);
        float4 a = f4[0], c4 = f4[1];
        int r = 3 + m * 8;
        h0[(r + 0) * KPAD + k] = a.x;  h0[(r + 1) * KPAD + k] = a.y;
        h0[(r + 2) * KPAD + k] = a.z;  h0[(r + 3) * KPAD + k] = a.w;
        h0[(r + 4) * KPAD + k] = c4.x; h0[(r + 5) * KPAD + k] = c4.y;
        h0[(r + 6) * KPAD + k] = c4.z; h0[(r + 7) * KPAD + k] = c4.w;
    }
    __syncthreads();

    int ot = tid & 31, kt = tid >> 5;

    mlp_layer<67, 64, 2>(h0, h1, ws + WS_W1T, b1, kt, ot);
    __syncthreads();
    mlp_layer<64, 128, 4>(h1, h2, ws + WS_W2T, b2, kt, ot);
    __syncthreads();

    { // L3 (128 -> 256) fused with maxpool over the thread's 4 k-rows
        float acc[4][8];
        #pragma unroll
        for (int oo = 0; oo < 8; oo++) {
            float bb = b3[ot * 8 + oo];
            #pragma unroll
            for (int kk = 0; kk < 4; kk++) acc[kk][oo] = bb;
        }
        const float* wt = ws + WS_W3T;
        for (int c = 0; c < 128; c++) {
            float4 hv = *(const float4*)&h2[c * KPAD + kt * 4];
            float ha[4] = {hv.x, hv.y, hv.z, hv.w};
            const float* wp = wt + c * 256 + ot * 8;
            float4 w0 = *(const float4*)wp, w1 = *(const float4*)(wp + 4);
            float wv[8] = {w0.x, w0.y, w0.z, w0.w, w1.x, w1.y, w1.z, w1.w};
            #pragma unroll
            for (int kk = 0; kk < 4; kk++)
                #pragma unroll
                for (int oo = 0; oo < 8; oo++) acc[kk][oo] += ha[kk] * wv[oo];
        }
        #pragma unroll
        for (int oo = 0; oo < 8; oo++) {
            float m = fmaxf(fmaxf(acc[0][oo], acc[1][oo]), fmaxf(acc[2][oo], acc[3][oo]));
            mxs[kt * 256 + ot * 8 + oo] = fmaxf(m, 0.f);   // relu(max) == max(relu)
        }
    }
    __syncthreads();

    { // reduce the 8 k-tiles, write feats
        int o = tid;
        float m = mxs[o];
        #pragma unroll
        for (int q = 1; q < 8; q++) m = fmaxf(m, mxs[q * 256 + o]);
        out[OUT_XYZ + g * 256 + o] = m;
    }
}

// ---------------------------------------------------------------------------
extern "C" void kernel_launch(void* const* d_in, const int* in_sizes, int n_in,
                              void* d_out, int out_size, void* d_ws, size_t ws_size,
                              hipStream_t stream) {
    const float* xyz  = (const float*)d_in[0];
    const float* feat = (const float*)d_in[1];
    const float* W1   = (const float*)d_in[2];
    const float* b1   = (const float*)d_in[3];
    const float* W2   = (const float*)d_in[4];
    const float* b2   = (const float*)d_in[5];
    const float* W3   = (const float*)d_in[6];
    const float* b3   = (const float*)d_in[7];
    float* out = (float*)d_out;
    float* ws  = (float*)d_ws;
    int*   grp = (int*)d_ws + WS_GRP;

    hipLaunchKernelGGL(prep_kernel, dim3(305), dim3(256), 0, stream, xyz, W1, W2, W3, ws);
    hipLaunchKernelGGL(fps_kernel, dim3(Bn), dim3(512), 0, stream, ws, out);
    hipLaunchKernelGGL(ballq_kernel, dim3(Bn * Sn / 4), dim3(256), 0, stream, ws, out, grp);
    hipLaunchKernelGGL(mlp_kernel, dim3(Bn * Sn), dim3(256), 0, stream,
                       xyz, feat, ws, grp, b1, b2, b3, out);
}

// Round 5
// 3151.957 us; speedup vs baseline: 1.0278x; 1.0278x over previous
//
#include <hip/hip_runtime.h>

// Problem constants
#define Bn 4
#define Nn 8192
#define Dn 64
#define Sn 2048
#define Kn 32
#define R2c 0.04f          // f32(0.2*0.2) — same bits as np/jax weak-scalar cast
#define OUT_XYZ (Bn*Sn*3)  // 24576 floats of new_xyz, then feats

// Workspace layout (units = 4-byte elements)
#define WS_XS  0            // [B*N] x coords (SoA)
#define WS_YS  32768
#define WS_ZS  65536
#define WS_W1T 98304        // W1^T [67][64]
#define WS_W2T 102592       // W2^T [64][128]
#define WS_W3T 110784       // W3^T [128][256]
#define WS_GRP 143552       // int grp_idx [B*S][K]

#define KPAD 36             // padded LDS row stride (floats) for h tiles

// ---------------------------------------------------------------------------
// Prep: transpose xyz -> SoA and weights -> [C][O] layout
// ---------------------------------------------------------------------------
__global__ __launch_bounds__(256) void prep_kernel(const float* __restrict__ xyz,
                                                   const float* __restrict__ W1,
                                                   const float* __restrict__ W2,
                                                   const float* __restrict__ W3,
                                                   float* __restrict__ ws) {
    int id = blockIdx.x * 256 + threadIdx.x;
    if (id < Bn * Nn) {
        ws[WS_XS + id] = xyz[id * 3 + 0];
        ws[WS_YS + id] = xyz[id * 3 + 1];
        ws[WS_ZS + id] = xyz[id * 3 + 2];
    }
    int i1 = id - Bn * Nn;
    if (i1 >= 0 && i1 < 64 * 67)  { int o = i1 / 67,  c = i1 % 67;  ws[WS_W1T + c * 64  + o] = W1[i1]; }
    int i2 = i1 - 64 * 67;
    if (i2 >= 0 && i2 < 128 * 64) { int o = i2 / 64,  c = i2 % 64;  ws[WS_W2T + c * 128 + o] = W2[i2]; }
    int i3 = i2 - 128 * 64;
    if (i3 >= 0 && i3 < 256 * 128){ int o = i3 / 128, c = i3 % 128; ws[WS_W3T + c * 256 + o] = W3[i3]; }
}

// ---------------------------------------------------------------------------
// Farthest point sampling — 1 barrier/step, no per-step global store.
//   * distance math mirrors numpy bit-exactly: separate mul/add,
//     (dx*dx+dy*dy)+dz*dz, fminf, contract off. float2 packing is purely
//     lane-packing (v_pk_*), per-element rounding unchanged.
//   * argmax via packed u64 key (float bits monotone for dist>=0; low word
//     = ~p gives min-index tie-break == np.argmax first occurrence)
//   * after the key reduce EVERY thread knows winner p and fetches its
//     coords from the SoA global arrays (uniform addr, L2-resident) —
//     no owner-publish phase, no second barrier.
//   * sKey double-buffered by step parity; centroid history kept in LDS
//     and dumped once at the end (removes vmcnt(0) drain at the barrier).
// One workgroup per batch, 512 threads, 16 pts/thread in registers.
// ---------------------------------------------------------------------------
__global__ __launch_bounds__(512) void fps_kernel(const float* __restrict__ ws,
                                                  float* __restrict__ out_xyz) {
    #pragma clang fp contract(off)
    const int b = blockIdx.x;
    const int tid = threadIdx.x;
    const float* xs = ws + WS_XS + b * Nn;
    const float* ys = ws + WS_YS + b * Nn;
    const float* zs = ws + WS_ZS + b * Nn;

    // 16 points/thread as 8 float2 pairs: pair i = points j=2i (.x), 2i+1 (.y)
    float2 px[8], py[8], pz[8], dist[8];
    #pragma unroll
    for (int i = 0; i < 8; i++) {
        int p0 = (2 * i) * 512 + tid;
        int p1 = (2 * i + 1) * 512 + tid;
        px[i].x = xs[p0]; px[i].y = xs[p1];
        py[i].x = ys[p0]; py[i].y = ys[p1];
        pz[i].x = zs[p0]; pz[i].y = zs[p1];
        dist[i].x = 1e10f; dist[i].y = 1e10f;   // matches np.float32(1e10)
    }

    __shared__ unsigned long long sKey[2][8];
    __shared__ float sHist[Sn * 3];

    // initial centroid = point 0 of the batch (broadcast global read, once)
    float cx = xs[0], cy = ys[0], cz = zs[0];

    for (int s = 0; s < Sn; s++) {
        const int par = s & 1;
        if (tid == 0) {                 // record carry centroid (LDS, cheap)
            sHist[s * 3 + 0] = cx;
            sHist[s * 3 + 1] = cy;
            sHist[s * 3 + 2] = cz;
        }
        // distance update + inline first-occurrence argmax — exact ref op order
        float lmax = -1.0f;
        int jbest = 0;
        #pragma unroll
        for (int i = 0; i < 8; i++) {
            // arithmetic for both elements first (SLP-packable, per-element
            // rounding identical to scalar)
            float dx0 = px[i].x - cx, dy0 = py[i].x - cy, dz0 = pz[i].x - cz;
            float dx1 = px[i].y - cx, dy1 = py[i].y - cy, dz1 = pz[i].y - cz;
            float d0 = (dx0 * dx0 + dy0 * dy0) + dz0 * dz0;
            float d1 = (dx1 * dx1 + dy1 * dy1) + dz1 * dz1;
            float dm0 = fminf(dist[i].x, d0);
            float dm1 = fminf(dist[i].y, d1);
            dist[i].x = dm0; dist[i].y = dm1;
            // sequential argmax in ascending j order (strict > keeps min p)
            bool c0 = dm0 > lmax;
            jbest = c0 ? (2 * i) : jbest;
            lmax  = c0 ? dm0 : lmax;
            bool c1 = dm1 > lmax;
            jbest = c1 ? (2 * i + 1) : jbest;
            lmax  = c1 ? dm1 : lmax;
        }
        int pbest = jbest * 512 + tid;
        unsigned long long key =
            ((unsigned long long)__float_as_uint(lmax) << 32) |
            (unsigned long long)(0xFFFFFFFFu - (unsigned)pbest);
        // wave butterfly max on the packed key (value major, min-p tie-break)
        #pragma unroll
        for (int off = 32; off >= 1; off >>= 1) {
            unsigned long long o = __shfl_xor(key, off);
            key = (key > o) ? key : o;
        }
        if ((tid & 63) == 0) sKey[par][tid >> 6] = key;
        __syncthreads();                   // the ONLY barrier per step
        // every thread reduces the 8 wave keys, then fetches winner coords
        unsigned long long k = sKey[par][0];
        #pragma unroll
        for (int i = 1; i < 8; i++) {
            unsigned long long o = sKey[par][i];
            k = (k > o) ? k : o;
        }
        int p = (int)(0xFFFFFFFFu - (unsigned)(k & 0xFFFFFFFFull));
        cx = xs[p];                        // uniform addr -> one transaction,
        cy = ys[p];                        // L2-resident (96 KB/batch)
        cz = zs[p];
    }

    __syncthreads();                       // sHist complete
    // coalesced dump: 6144 floats = 1536 float4, 3 per thread
    float4* o4 = (float4*)(out_xyz + b * Sn * 3);
    const float4* h4 = (const float4*)sHist;
    #pragma unroll
    for (int i = tid; i < Sn * 3 / 4; i += 512) o4[i] = h4[i];
}

// ---------------------------------------------------------------------------
// Ball query, f32, mirroring the numpy transpile with einsum lowered to
// BLAS sgemm: the k=3 dot is an FMA chain acc=fma(a_k,b_k,acc) from 0.
// Norm terms are plain mul/add ((x2+y2)+z2). sq = (t1+t2) - 2*dot.
// One wave per (b,s). First K hits in ascending index order via
// ballot + prefix-popcount, early exit, pad with first hit.
// ---------------------------------------------------------------------------
__global__ __launch_bounds__(256) void ballq_kernel(const float* __restrict__ ws,
                                                    const float* __restrict__ newxyz,
                                                    int* __restrict__ grp) {
    #pragma clang fp contract(off)
    int t = blockIdx.x * 256 + threadIdx.x;
    int wid = t >> 6;            // 0..8191  (b*S+s)
    int lane = t & 63;
    int b = wid >> 11;
    const float* xs = ws + WS_XS + b * Nn;
    const float* ys = ws + WS_YS + b * Nn;
    const float* zs = ws + WS_ZS + b * Nn;

    float nx = newxyz[wid * 3 + 0], ny = newxyz[wid * 3 + 1], nz = newxyz[wid * 3 + 2];
    float a2 = (nx * nx + ny * ny) + nz * nz;   // np.sum(new**2, -1): plain mul/add

    int total = 0;
    int firstp = 0;
    for (int c = 0; c < Nn / 64; c++) {
        int p = c * 64 + lane;
        float x = xs[p], y = ys[p], z = zs[p];
        float bv = (x * x + y * y) + z * z;          // np.sum(xyz**2, -1)
        // sgemm k-loop: FMA rank-1 updates in order, acc starts at 0
        float dot = __builtin_fmaf(nx, x, 0.0f);
        dot = __builtin_fmaf(ny, y, dot);
        dot = __builtin_fmaf(nz, z, dot);
        float sq = (a2 + bv) - 2.0f * dot;           // (t1+t2) - 2*e
        bool hit = !(sq > R2c);
        unsigned long long mask = __ballot(hit);
        if (mask) {
            if (total == 0) firstp = c * 64 + (__ffsll(mask) - 1);
            int rank = __popcll(mask & ((1ull << lane) - 1ull));
            int slot = total + rank;
            if (hit && slot < Kn) grp[wid * Kn + slot] = p;
            total += (int)__popcll(mask);
            if (total >= Kn) break;
        }
    }
    if (lane >= total && lane < Kn) grp[wid * Kn + lane] = firstp;  // pad w/ first hit
}

// ---------------------------------------------------------------------------
// Fused gather + 3-layer MLP + maxpool (f32 — error ~1e-5 « 0.064 budget).
// One workgroup per (b,s) group. h tiles live transposed [C][K] in LDS
// (row stride KPAD=36, bank-friendly, 16B aligned). Weights read from global
// transposed copies (L1/L2 resident). Thread tile: 4 k-rows x WO outputs.
// ---------------------------------------------------------------------------
template<int C, int O, int WO>
__device__ __forceinline__ void mlp_layer(const float* inT, float* outT,
                                          const float* __restrict__ wt,
                                          const float* __restrict__ bias,
                                          int kt, int ot) {
    float acc[4][WO];
    #pragma unroll
    for (int oo = 0; oo < WO; oo++) {
        float bb = bias[ot * WO + oo];
        #pragma unroll
        for (int kk = 0; kk < 4; kk++) acc[kk][oo] = bb;
    }
    for (int c = 0; c < C; c++) {
        float4 hv = *(const float4*)&inT[c * KPAD + kt * 4];
        float ha[4] = {hv.x, hv.y, hv.z, hv.w};
        const float* wp = wt + c * O + ot * WO;
        float wv[WO];
        if constexpr (WO == 2) {
            float2 w = *(const float2*)wp; wv[0] = w.x; wv[1] = w.y;
        } else if constexpr (WO == 4) {
            float4 w = *(const float4*)wp; wv[0] = w.x; wv[1] = w.y; wv[2] = w.z; wv[3] = w.w;
        } else {
            float4 w0 = *(const float4*)wp, w1 = *(const float4*)(wp + 4);
            wv[0] = w0.x; wv[1] = w0.y; wv[2] = w0.z; wv[3] = w0.w;
            wv[4] = w1.x; wv[5] = w1.y; wv[6] = w1.z; wv[7] = w1.w;
        }
        #pragma unroll
        for (int kk = 0; kk < 4; kk++)
            #pragma unroll
            for (int oo = 0; oo < WO; oo++) acc[kk][oo] += ha[kk] * wv[oo];
    }
    #pragma unroll
    for (int oo = 0; oo < WO; oo++) {
        int o = ot * WO + oo;
        float4 st;
        st.x = fmaxf(acc[0][oo], 0.f); st.y = fmaxf(acc[1][oo], 0.f);
        st.z = fmaxf(acc[2][oo], 0.f); st.w = fmaxf(acc[3][oo], 0.f);
        *(float4*)&outT[o * KPAD + kt * 4] = st;
    }
}

__global__ __launch_bounds__(256) void mlp_kernel(const float* __restrict__ xyz,
                                                  const float* __restrict__ feat,
                                                  const float* __restrict__ ws,
                                                  const int* __restrict__ grp,
                                                  const float* __restrict__ b1,
                                                  const float* __restrict__ b2,
                                                  const float* __restrict__ b3,
                                                  float* __restrict__ out) {
    __shared__ float h0[67 * KPAD];
    __shared__ float h1[64 * KPAD];
    __shared__ float h2[128 * KPAD];
    __shared__ float mxs[8 * 256];
    __shared__ int   sIdx[Kn];
    __shared__ float sCent[3];

    int g = blockIdx.x;            // b*S + s
    int b = g >> 11;
    int tid = threadIdx.x;

    if (tid < Kn) sIdx[tid] = grp[g * Kn + tid];
    if (tid == 0) { sCent[0] = out[g*3]; sCent[1] = out[g*3+1]; sCent[2] = out[g*3+2]; }
    __syncthreads();

    { // gather: 8 threads per neighbor row
        int k = tid >> 3, m = tid & 7;
        int idx = sIdx[k];
        int base = b * Nn + idx;
        if (m == 0) {
            h0[0 * KPAD + k] = xyz[base * 3 + 0] - sCent[0];
            h0[1 * KPAD + k] = xyz[base * 3 + 1] - sCent[1];
            h0[2 * KPAD + k] = xyz[base * 3 + 2] - sCent[2];
        }
        const float4* f4 = (const float4*)(feat + base * 64 + m * 8);
        float4 a = f4[0], c4 = f4[1];
        int r = 3 + m * 8;
        h0[(r + 0) * KPAD + k] = a.x;  h0[(r + 1) * KPAD + k] = a.y;
        h0[(r + 2) * KPAD + k] = a.z;  h0[(r + 3) * KPAD + k] = a.w;
        h0[(r + 4) * KPAD + k] = c4.x; h0[(r + 5) * KPAD + k] = c4.y;
        h0[(r + 6) * KPAD + k] = c4.z; h0[(r + 7) * KPAD + k] = c4.w;
    }
    __syncthreads();

    int ot = tid & 31, kt = tid >> 5;

    mlp_layer<67, 64, 2>(h0, h1, ws + WS_W1T, b1, kt, ot);
    __syncthreads();
    mlp_layer<64, 128, 4>(h1, h2, ws + WS_W2T, b2, kt, ot);
    __syncthreads();

    { // L3 (128 -> 256) fused with maxpool over the thread's 4 k-rows
        float acc[4][8];
        #pragma unroll
        for (int oo = 0; oo < 8; oo++) {
            float bb = b3[ot * 8 + oo];
            #pragma unroll
            for (int kk = 0; kk < 4; kk++) acc[kk][oo] = bb;
        }
        const float* wt = ws + WS_W3T;
        for (int c = 0; c < 128; c++) {
            float4 hv = *(const float4*)&h2[c * KPAD + kt * 4];
            float ha[4] = {hv.x, hv.y, hv.z, hv.w};
            const float* wp = wt + c * 256 + ot * 8;
            float4 w0 = *(const float4*)wp, w1 = *(const float4*)(wp + 4);
            float wv[8] = {w0.x, w0.y, w0.z, w0.w, w1.x, w1.y, w1.z, w1.w};
            #pragma unroll
            for (int kk = 0; kk < 4; kk++)
                #pragma unroll
                for (int oo = 0; oo < 8; oo++) acc[kk][oo] += ha[kk] * wv[oo];
        }
        #pragma unroll
        for (int oo = 0; oo < 8; oo++) {
            float m = fmaxf(fmaxf(acc[0][oo], acc[1][oo]), fmaxf(acc[2][oo], acc[3][oo]));
            mxs[kt * 256 + ot * 8 + oo] = fmaxf(m, 0.f);   // relu(max) == max(relu)
        }
    }
    __syncthreads();

    { // reduce the 8 k-tiles, write feats
        int o = tid;
        float m = mxs[o];
        #pragma unroll
        for (int q = 1; q < 8; q++) m = fmaxf(m, mxs[q * 256 + o]);
        out[OUT_XYZ + g * 256 + o] = m;
    }
}

// ---------------------------------------------------------------------------
extern "C" void kernel_launch(void* const* d_in, const int* in_sizes, int n_in,
                              void* d_out, int out_size, void* d_ws, size_t ws_size,
                              hipStream_t stream) {
    const float* xyz  = (const float*)d_in[0];
    const float* feat = (const float*)d_in[1];
    const float* W1   = (const float*)d_in[2];
    const float* b1   = (const float*)d_in[3];
    const float* W2   = (const float*)d_in[4];
    const float* b2   = (const float*)d_in[5];
    const float* W3   = (const float*)d_in[6];
    const float* b3   = (const float*)d_in[7];
    float* out = (float*)d_out;
    float* ws  = (float*)d_ws;
    int*   grp = (int*)d_ws + WS_GRP;

    hipLaunchKernelGGL(prep_kernel, dim3(305), dim3(256), 0, stream, xyz, W1, W2, W3, ws);
    hipLaunchKernelGGL(fps_kernel, dim3(Bn), dim3(512), 0, stream, ws, out);
    hipLaunchKernelGGL(ballq_kernel, dim3(Bn * Sn / 4), dim3(256), 0, stream, ws, out, grp);
    hipLaunchKernelGGL(mlp_kernel, dim3(Bn * Sn), dim3(256), 0, stream,
                       xyz, feat, ws, grp, b1, b2, b3, out);
}

// Round 6
// 3023.433 us; speedup vs baseline: 1.0715x; 1.0425x over previous
//
#include <hip/hip_runtime.h>

// Problem constants
#define Bn 4
#define Nn 8192
#define Dn 64
#define Sn 2048
#define Kn 32
#define R2c 0.04f          // f32(0.2*0.2) — same bits as np/jax weak-scalar cast
#define OUT_XYZ (Bn*Sn*3)  // 24576 floats of new_xyz, then feats

// Workspace layout (units = 4-byte elements)
#define WS_XS  0            // [B*N] x coords (SoA)
#define WS_YS  32768
#define WS_ZS  65536
#define WS_W1T 98304        // W1^T [67][64]
#define WS_W2T 102592       // W2^T [64][128]
#define WS_W3T 110784       // W3^T [128][256]
#define WS_GRP 143552       // int grp_idx [B*S][K]

#define KPAD 36             // padded LDS row stride (floats) for h tiles

// ---------------------------------------------------------------------------
// Prep: transpose xyz -> SoA and weights -> [C][O] layout
// ---------------------------------------------------------------------------
__global__ __launch_bounds__(256) void prep_kernel(const float* __restrict__ xyz,
                                                   const float* __restrict__ W1,
                                                   const float* __restrict__ W2,
                                                   const float* __restrict__ W3,
                                                   float* __restrict__ ws) {
    int id = blockIdx.x * 256 + threadIdx.x;
    if (id < Bn * Nn) {
        ws[WS_XS + id] = xyz[id * 3 + 0];
        ws[WS_YS + id] = xyz[id * 3 + 1];
        ws[WS_ZS + id] = xyz[id * 3 + 2];
    }
    int i1 = id - Bn * Nn;
    if (i1 >= 0 && i1 < 64 * 67)  { int o = i1 / 67,  c = i1 % 67;  ws[WS_W1T + c * 64  + o] = W1[i1]; }
    int i2 = i1 - 64 * 67;
    if (i2 >= 0 && i2 < 128 * 64) { int o = i2 / 64,  c = i2 % 64;  ws[WS_W2T + c * 128 + o] = W2[i2]; }
    int i3 = i2 - 128 * 64;
    if (i3 >= 0 && i3 < 256 * 128){ int o = i3 / 128, c = i3 % 128; ws[WS_W3T + c * 256 + o] = W3[i3]; }
}

// ---------------------------------------------------------------------------
// Farthest point sampling — minimal-issue dist loop (R3) + 2 barriers/step
// (R5), f32-only reduction.
//   * distance math mirrors numpy bit-exactly: separate mul/add,
//     (dx*dx+dy*dy)+dz*dz, fminf, contract off.
//   * loop tracks only the max VALUE (fmax tree is reorder-invariant);
//     the argmax INDEX is recovered post-reduce by a rare exec-masked
//     rescan (only threads with lmax==gmax enter; descending-j scan gives
//     first occurrence = min p = np.argmax semantics) + LDS atomicMin.
//   * sMin parity-double-buffered, re-armed after B1 of the next step
//     (validated in R1/R2); sPart single-buffered (B2 separates use/reuse).
//   * centroid history in LDS, dumped coalesced at the end (keeps global
//     stores out of the per-step barrier path).
// One workgroup per batch, 512 threads, 16 pts/thread in registers.
// ---------------------------------------------------------------------------
__global__ __launch_bounds__(512) void fps_kernel(const float* __restrict__ ws,
                                                  float* __restrict__ out_xyz) {
    #pragma clang fp contract(off)
    const int b = blockIdx.x;
    const int tid = threadIdx.x;
    const float* xs = ws + WS_XS + b * Nn;
    const float* ys = ws + WS_YS + b * Nn;
    const float* zs = ws + WS_ZS + b * Nn;

    float px[16], py[16], pz[16], dist[16];
    #pragma unroll
    for (int j = 0; j < 16; j++) {
        int p = j * 512 + tid;           // coalesced: lane-contiguous
        px[j] = xs[p]; py[j] = ys[p]; pz[j] = zs[p];
        dist[j] = 1e10f;                 // matches np.float32(1e10)
    }

    __shared__ float sPart[8];
    __shared__ int   sMin[2];
    __shared__ float sHist[Sn * 3];

    if (tid == 0) { sMin[0] = 0x7fffffff; sMin[1] = 0x7fffffff; }
    // initial centroid = point 0 of the batch (broadcast global read, once)
    float cx = xs[0], cy = ys[0], cz = zs[0];

    for (int s = 0; s < Sn; s++) {
        const int par = s & 1;
        if (tid == 0) {                 // record carry centroid (LDS, cheap)
            sHist[s * 3 + 0] = cx;
            sHist[s * 3 + 1] = cy;
            sHist[s * 3 + 2] = cz;
        }
        // minimal dist update: 3 sub, 3 mul, 2 add, fmin, fmax per point —
        // exact reference op order, no index tracking here
        float lmax = -1.0f;
        #pragma unroll
        for (int j = 0; j < 16; j++) {
            float dx = px[j] - cx, dy = py[j] - cy, dz = pz[j] - cz;
            float d  = (dx * dx + dy * dy) + dz * dz;
            float dm = fminf(dist[j], d);
            dist[j] = dm;
            lmax = fmaxf(lmax, dm);
        }
        // f32 wave butterfly max (all 64 lanes converge)
        float w = lmax;
        #pragma unroll
        for (int off = 32; off >= 1; off >>= 1) w = fmaxf(w, __shfl_xor(w, off));
        if ((tid & 63) == 0) sPart[tid >> 6] = w;
        __syncthreads();                               // B1: wave maxima ready
        if (tid == 0) sMin[1 - par] = 0x7fffffff;      // re-arm for step s+1
        float4 p0 = *(const float4*)&sPart[0];
        float4 p1 = *(const float4*)&sPart[4];
        float gmax = fmaxf(fmaxf(fmaxf(p0.x, p0.y), fmaxf(p0.z, p0.w)),
                           fmaxf(fmaxf(p1.x, p1.y), fmaxf(p1.z, p1.w)));
        // rare branch: only threads holding the global max enter (~1 thread);
        // descending-j scan keeps the smallest j -> min p (first occurrence)
        if (lmax == gmax) {
            int pbest = 0x7fffffff;
            #pragma unroll
            for (int j = 15; j >= 0; j--)
                if (dist[j] == gmax) pbest = j * 512 + tid;
            atomicMin(&sMin[par], pbest);
        }
        __syncthreads();                               // B2: winner final
        int p = sMin[par];
        cx = xs[p];                        // uniform addr -> one transaction,
        cy = ys[p];                        // L2-resident (96 KB/batch)
        cz = zs[p];
    }

    __syncthreads();                       // sHist complete
    // coalesced dump: 6144 floats = 1536 float4, 3 per thread
    float4* o4 = (float4*)(out_xyz + b * Sn * 3);
    const float4* h4 = (const float4*)sHist;
    #pragma unroll
    for (int i = tid; i < Sn * 3 / 4; i += 512) o4[i] = h4[i];
}

// ---------------------------------------------------------------------------
// Ball query, f32, mirroring the numpy transpile with einsum lowered to
// BLAS sgemm: the k=3 dot is an FMA chain acc=fma(a_k,b_k,acc) from 0.
// Norm terms are plain mul/add ((x2+y2)+z2). sq = (t1+t2) - 2*dot.
// One wave per (b,s). First K hits in ascending index order via
// ballot + prefix-popcount, early exit, pad with first hit.
// ---------------------------------------------------------------------------
__global__ __launch_bounds__(256) void ballq_kernel(const float* __restrict__ ws,
                                                    const float* __restrict__ newxyz,
                                                    int* __restrict__ grp) {
    #pragma clang fp contract(off)
    int t = blockIdx.x * 256 + threadIdx.x;
    int wid = t >> 6;            // 0..8191  (b*S+s)
    int lane = t & 63;
    int b = wid >> 11;
    const float* xs = ws + WS_XS + b * Nn;
    const float* ys = ws + WS_YS + b * Nn;
    const float* zs = ws + WS_ZS + b * Nn;

    float nx = newxyz[wid * 3 + 0], ny = newxyz[wid * 3 + 1], nz = newxyz[wid * 3 + 2];
    float a2 = (nx * nx + ny * ny) + nz * nz;   // np.sum(new**2, -1): plain mul/add

    int total = 0;
    int firstp = 0;
    for (int c = 0; c < Nn / 64; c++) {
        int p = c * 64 + lane;
        float x = xs[p], y = ys[p], z = zs[p];
        float bv = (x * x + y * y) + z * z;          // np.sum(xyz**2, -1)
        // sgemm k-loop: FMA rank-1 updates in order, acc starts at 0
        float dot = __builtin_fmaf(nx, x, 0.0f);
        dot = __builtin_fmaf(ny, y, dot);
        dot = __builtin_fmaf(nz, z, dot);
        float sq = (a2 + bv) - 2.0f * dot;           // (t1+t2) - 2*e
        bool hit = !(sq > R2c);
        unsigned long long mask = __ballot(hit);
        if (mask) {
            if (total == 0) firstp = c * 64 + (__ffsll(mask) - 1);
            int rank = __popcll(mask & ((1ull << lane) - 1ull));
            int slot = total + rank;
            if (hit && slot < Kn) grp[wid * Kn + slot] = p;
            total += (int)__popcll(mask);
            if (total >= Kn) break;
        }
    }
    if (lane >= total && lane < Kn) grp[wid * Kn + lane] = firstp;  // pad w/ first hit
}

// ---------------------------------------------------------------------------
// Fused gather + 3-layer MLP + maxpool (f32 — error ~1e-5 « 0.064 budget).
// One workgroup per (b,s) group. h tiles live transposed [C][K] in LDS
// (row stride KPAD=36, bank-friendly, 16B aligned). Weights read from global
// transposed copies (L1/L2 resident). Thread tile: 4 k-rows x WO outputs.
// ---------------------------------------------------------------------------
template<int C, int O, int WO>
__device__ __forceinline__ void mlp_layer(const float* inT, float* outT,
                                          const float* __restrict__ wt,
                                          const float* __restrict__ bias,
                                          int kt, int ot) {
    float acc[4][WO];
    #pragma unroll
    for (int oo = 0; oo < WO; oo++) {
        float bb = bias[ot * WO + oo];
        #pragma unroll
        for (int kk = 0; kk < 4; kk++) acc[kk][oo] = bb;
    }
    for (int c = 0; c < C; c++) {
        float4 hv = *(const float4*)&inT[c * KPAD + kt * 4];
        float ha[4] = {hv.x, hv.y, hv.z, hv.w};
        const float* wp = wt + c * O + ot * WO;
        float wv[WO];
        if constexpr (WO == 2) {
            float2 w = *(const float2*)wp; wv[0] = w.x; wv[1] = w.y;
        } else if constexpr (WO == 4) {
            float4 w = *(const float4*)wp; wv[0] = w.x; wv[1] = w.y; wv[2] = w.z; wv[3] = w.w;
        } else {
            float4 w0 = *(const float4*)wp, w1 = *(const float4*)(wp + 4);
            wv[0] = w0.x; wv[1] = w0.y; wv[2] = w0.z; wv[3] = w0.w;
            wv[4] = w1.x; wv[5] = w1.y; wv[6] = w1.z; wv[7] = w1.w;
        }
        #pragma unroll
        for (int kk = 0; kk < 4; kk++)
            #pragma unroll
            for (int oo = 0; oo < WO; oo++) acc[kk][oo] += ha[kk] * wv[oo];
    }
    #pragma unroll
    for (int oo = 0; oo < WO; oo++) {
        int o = ot * WO + oo;
        float4 st;
        st.x = fmaxf(acc[0][oo], 0.f); st.y = fmaxf(acc[1][oo], 0.f);
        st.z = fmaxf(acc[2][oo], 0.f); st.w = fmaxf(acc[3][oo], 0.f);
        *(float4*)&outT[o * KPAD + kt * 4] = st;
    }
}

__global__ __launch_bounds__(256) void mlp_kernel(const float* __restrict__ xyz,
                                                  const float* __restrict__ feat,
                                                  const float* __restrict__ ws,
                                                  const int* __restrict__ grp,
                                                  const float* __restrict__ b1,
                                                  const float* __restrict__ b2,
                                                  const float* __restrict__ b3,
                                                  float* __restrict__ out) {
    __shared__ float h0[67 * KPAD];
    __shared__ float h1[64 * KPAD];
    __shared__ float h2[128 * KPAD];
    __shared__ float mxs[8 * 256];
    __shared__ int   sIdx[Kn];
    __shared__ float sCent[3];

    int g = blockIdx.x;            // b*S + s
    int b = g >> 11;
    int tid = threadIdx.x;

    if (tid < Kn) sIdx[tid] = grp[g * Kn + tid];
    if (tid == 0) { sCent[0] = out[g*3]; sCent[1] = out[g*3+1]; sCent[2] = out[g*3+2]; }
    __syncthreads();

    { // gather: 8 threads per neighbor row
        int k = tid >> 3, m = tid & 7;
        int idx = sIdx[k];
        int base = b * Nn + idx;
        if (m == 0) {
            h0[0 * KPAD + k] = xyz[base * 3 + 0] - sCent[0];
            h0[1 * KPAD + k] = xyz[base * 3 + 1] - sCent[1];
            h0[2 * KPAD + k] = xyz[base * 3 + 2] - sCent[2];
        }
        const float4* f4 = (const float4*)(feat + base * 64 + m * 8);
        float4 a = f4[0], c4 = f4[1];
        int r = 3 + m * 8;
        h0[(r + 0) * KPAD + k] = a.x;  h0[(r + 1) * KPAD + k] = a.y;
        h0[(r + 2) * KPAD + k] = a.z;  h0[(r + 3) * KPAD + k] = a.w;
        h0[(r + 4) * KPAD + k] = c4.x; h0[(r + 5) * KPAD + k] = c4.y;
        h0[(r + 6) * KPAD + k] = c4.z; h0[(r + 7) * KPAD + k] = c4.w;
    }
    __syncthreads();

    int ot = tid & 31, kt = tid >> 5;

    mlp_layer<67, 64, 2>(h0, h1, ws + WS_W1T, b1, kt, ot);
    __syncthreads();
    mlp_layer<64, 128, 4>(h1, h2, ws + WS_W2T, b2, kt, ot);
    __syncthreads();

    { // L3 (128 -> 256) fused with maxpool over the thread's 4 k-rows
        float acc[4][8];
        #pragma unroll
        for (int oo = 0; oo < 8; oo++) {
            float bb = b3[ot * 8 + oo];
            #pragma unroll
            for (int kk = 0; kk < 4; kk++) acc[kk][oo] = bb;
        }
        const float* wt = ws + WS_W3T;
        for (int c = 0; c < 128; c++) {
            float4 hv = *(const float4*)&h2[c * KPAD + kt * 4];
            float ha[4] = {hv.x, hv.y, hv.z, hv.w};
            const float* wp = wt + c * 256 + ot * 8;
            float4 w0 = *(const float4*)wp, w1 = *(const float4*)(wp + 4);
            float wv[8] = {w0.x, w0.y, w0.z, w0.w, w1.x, w1.y, w1.z, w1.w};
            #pragma unroll
            for (int kk = 0; kk < 4; kk++)
                #pragma unroll
                for (int oo = 0; oo < 8; oo++) acc[kk][oo] += ha[kk] * wv[oo];
        }
        #pragma unroll
        for (int oo = 0; oo < 8; oo++) {
            float m = fmaxf(fmaxf(acc[0][oo], acc[1][oo]), fmaxf(acc[2][oo], acc[3][oo]));
            mxs[kt * 256 + ot * 8 + oo] = fmaxf(m, 0.f);   // relu(max) == max(relu)
        }
    }
    __syncthreads();

    { // reduce the 8 k-tiles, write feats
        int o = tid;
        float m = mxs[o];
        #pragma unroll
        for (int q = 1; q < 8; q++) m = fmaxf(m, mxs[q * 256 + o]);
        out[OUT_XYZ + g * 256 + o] = m;
    }
}

// ---------------------------------------------------------------------------
extern "C" void kernel_launch(void* const* d_in, const int* in_sizes, int n_in,
                              void* d_out, int out_size, void* d_ws, size_t ws_size,
                              hipStream_t stream) {
    const float* xyz  = (const float*)d_in[0];
    const float* feat = (const float*)d_in[1];
    const float* W1   = (const float*)d_in[2];
    const float* b1   = (const float*)d_in[3];
    const float* W2   = (const float*)d_in[4];
    const float* b2   = (const float*)d_in[5];
    const float* W3   = (const float*)d_in[6];
    const float* b3   = (const float*)d_in[7];
    float* out = (float*)d_out;
    float* ws  = (float*)d_ws;
    int*   grp = (int*)d_ws + WS_GRP;

    hipLaunchKernelGGL(prep_kernel, dim3(305), dim3(256), 0, stream, xyz, W1, W2, W3, ws);
    hipLaunchKernelGGL(fps_kernel, dim3(Bn), dim3(512), 0, stream, ws, out);
    hipLaunchKernelGGL(ballq_kernel, dim3(Bn * Sn / 4), dim3(256), 0, stream, ws, out, grp);
    hipLaunchKernelGGL(mlp_kernel, dim3(Bn * Sn), dim3(256), 0, stream,
                       xyz, feat, ws, grp, b1, b2, b3, out);
}